// Round 6
// baseline (40.592 us; speedup 1.0000x reference)
//
#include <hip/hip_runtime.h>
#include <math.h>

#define MAX_T 2048

// ---------------- Kernel 1: score = sigmoid(feat . W + b) ----------------
// One wave (64 lanes) per (b,t) row. float4 coalesced loads.
__global__ void score_kernel(const float* __restrict__ feat,
                             const float* __restrict__ W,
                             const float* __restrict__ bias,
                             float* __restrict__ score,
                             int nrows, int D) {
  int row = blockIdx.x * 4 + (threadIdx.x >> 6);
  int lane = threadIdx.x & 63;
  if (row >= nrows) return;
  const float4* f4 = (const float4*)(feat + (size_t)row * D);
  const float4* w4 = (const float4*)W;
  float acc = 0.f;
  int n4 = D >> 2;
  for (int idx = lane; idx < n4; idx += 64) {
    float4 a = f4[idx];
    float4 w = w4[idx];
    acc += a.x * w.x + a.y * w.y + a.z * w.z + a.w * w.w;
  }
#pragma unroll
  for (int off = 32; off > 0; off >>= 1) acc += __shfl_xor(acc, off, 64);
  if (lane == 0) {
    float x = acc + bias[0];
    score[row] = 1.f / (1.f + expf(-x));
  }
}

// ---------------- Kernel 2: valley detect -> vi table ----------------
// One block (256 threads) per batch element. vi[j] = frame index of valley j.
// Valleys forced at t=0 and t=hl-1, so hn>=2 and vi[hn-1]==hl-1.
// Segment k = [vi[k-1], vi[k+1]) with vi[-1]:=0; last segment (k==hn-1)
// = [vi[hn-2], hl-1) == [vi[hn-2], vi[hn-1]).
__global__ void seg_kernel(const float* __restrict__ score,
                           const int* __restrict__ hlens,
                           int* __restrict__ vi_ws,
                           int* __restrict__ hn_ws,
                           float* __restrict__ hn_out,
                           int T, int M) {
  int b = blockIdx.x;
  int tid = threadIdx.x;
  __shared__ float s[MAX_T];
  __shared__ unsigned char fl[MAX_T];
  __shared__ int vi[MAX_T];
  __shared__ int wsum[4];

  const float* sr = score + (size_t)b * T;
  int hl = hlens[b];

  for (int t = tid; t < T; t += 256) s[t] = sr[t];
  __syncthreads();

  for (int t = tid; t < T; t += 256) {
    bool f;
    if (t >= hl) {
      f = false;
    } else if (t == 0 || t == hl - 1) {
      f = true;
    } else {
      float c = s[t];
      f = (c >= s[t - 1]) && (c >= s[t + 1]);
    }
    fl[t] = f ? (unsigned char)1 : (unsigned char)0;
  }
  __syncthreads();

  // blocked scan: per-thread chunk count -> wave shfl scan -> 4-wave combine
  int C = (T + 255) / 256;
  int lo = tid * C;
  int hi = lo + C; if (hi > T) hi = T; if (lo > T) lo = T;
  int cnt = 0;
  for (int t = lo; t < hi; ++t) cnt += fl[t];

  int lane = tid & 63, wid = tid >> 6;
  int incl = cnt;
#pragma unroll
  for (int off = 1; off < 64; off <<= 1) {
    int v = __shfl_up(incl, off, 64);
    if (lane >= off) incl += v;
  }
  if (lane == 63) wsum[wid] = incl;
  __syncthreads();
  int wofs = 0;
#pragma unroll
  for (int w = 0; w < 4; ++w) wofs += (w < wid) ? wsum[w] : 0;
  int hn = wsum[0] + wsum[1] + wsum[2] + wsum[3];
  int excl = wofs + incl - cnt;
  for (int t = lo; t < hi; ++t) {
    if (fl[t]) vi[excl++] = t;
  }
  __syncthreads();

  for (int j = tid; j < M; j += 256) {
    vi_ws[(size_t)b * M + j] = (j < hn) ? vi[j] : 0;
  }
  if (tid == 0) {
    hn_ws[b] = hn;
    hn_out[b] = (float)hn;
  }
}

// ---------------- Kernel 3: direct per-segment pool ----------------
// One 128-thread block per (b,k): lane d4 covers float4 d4 of D=512.
// Segment k = [vi[k-1], vi[k+1]) (vi[-1]:=0; k==hn-1 ends at vi[hn-1]=hl-1).
// Re-reads feat ~2x but from L3 (feat fully cache-resident after kernel 1);
// 7840 blocks ~= 15 waves/SIMD for latency hiding.
__global__ __launch_bounds__(128) void pool_kernel(
    const float* __restrict__ feat, const float* __restrict__ score,
    const int* __restrict__ vi_ws, const int* __restrict__ hn_ws,
    float* __restrict__ out, int T, int D, int M) {
  int gid = blockIdx.x;
  int b = gid / M;
  int k = gid - b * M;
  int lane = threadIdx.x;                 // 128 lanes, float4 covers D=512
  float4* o4 = (float4*)(out + (size_t)gid * (size_t)D);
  int hn = hn_ws[b];
  if (k >= hn) {
    o4[lane] = make_float4(0.f, 0.f, 0.f, 0.f);
    return;
  }
  const int* vi = vi_ws + (size_t)b * M;
  int as = (k == 0) ? 0 : vi[k - 1];
  int ae = (k == hn - 1) ? vi[hn - 1] : vi[k + 1];

  const float* sr = score + (size_t)b * T;
  const float4* fr = (const float4*)(feat + (size_t)b * T * (size_t)D);
  int n4 = D >> 2;                        // 128

  float4 a = make_float4(0.f, 0.f, 0.f, 0.f);
  float ss = 0.f;
  for (int t = as; t < ae; ++t) {
    float sc = sr[t];
    float4 f = fr[(size_t)t * n4 + lane];
    a.x += sc * f.x; a.y += sc * f.y; a.z += sc * f.z; a.w += sc * f.w;
    ss += sc;
  }
  float inv = 1.f / (ss + 1e-10f);
  o4[lane] = make_float4(a.x * inv, a.y * inv, a.z * inv, a.w * inv);
}

extern "C" void kernel_launch(void* const* d_in, const int* in_sizes, int n_in,
                              void* d_out, int out_size, void* d_ws, size_t ws_size,
                              hipStream_t stream) {
  const float* feat = (const float*)d_in[0];
  const float* W    = (const float*)d_in[1];
  const float* bias = (const float*)d_in[2];
  const int* hlens  = (const int*)d_in[3];

  int D = in_sizes[1];                 // 512
  int B = in_sizes[3];                 // 16
  int T = in_sizes[0] / (B * D);       // 2000
  int M = (out_size - B - B * T) / (B * D);  // data-dependent max segments

  float* out      = (float*)d_out;
  float* hn_out   = out + (size_t)B * M * D;      // [B] (as float)
  float* score    = hn_out + B;                   // [B, T]

  // ws layout: vi[B*M] int | hn_ws[B] int
  int* vi_ws = (int*)d_ws;
  int* hn_ws = vi_ws + (size_t)B * M;

  int nrows = B * T;
  score_kernel<<<(nrows + 3) / 4, 256, 0, stream>>>(feat, W, bias, score, nrows, D);
  seg_kernel<<<B, 256, 0, stream>>>(score, hlens, vi_ws, hn_ws, hn_out, T, M);
  pool_kernel<<<B * M, 128, 0, stream>>>(feat, score, vi_ws, hn_ws, out, T, D, M);
}

// Round 7
// 37.510 us; speedup vs baseline: 1.0822x; 1.0822x over previous
//
#include <hip/hip_runtime.h>
#include <math.h>

#define MAX_T 2048
#define SEG_P 2   // segments per 128-lane pool block
#define NXCD 8

// ---------------- Kernel 1: score = sigmoid(feat . W + b) ----------------
// One wave (64 lanes) per (b,t) row. float4 coalesced loads.
__global__ void score_kernel(const float* __restrict__ feat,
                             const float* __restrict__ W,
                             const float* __restrict__ bias,
                             float* __restrict__ score,
                             int nrows, int D) {
  int row = blockIdx.x * 4 + (threadIdx.x >> 6);
  int lane = threadIdx.x & 63;
  if (row >= nrows) return;
  const float4* f4 = (const float4*)(feat + (size_t)row * D);
  const float4* w4 = (const float4*)W;
  float acc = 0.f;
  int n4 = D >> 2;
  for (int idx = lane; idx < n4; idx += 64) {
    float4 a = f4[idx];
    float4 w = w4[idx];
    acc += a.x * w.x + a.y * w.y + a.z * w.z + a.w * w.w;
  }
#pragma unroll
  for (int off = 32; off > 0; off >>= 1) acc += __shfl_xor(acc, off, 64);
  if (lane == 0) {
    float x = acc + bias[0];
    score[row] = 1.f / (1.f + expf(-x));
  }
}

// ---------------- Kernel 2: valley detect -> vi table ----------------
// One block (256 threads) per batch element. vi[j] = frame index of valley j.
// Atom j := [vi[j-1], vi[j]) with vi[-1]:=0 (atom 0 empty since vi[0]==0).
// Segment k = atom k U atom k+1 (k<hn-1); segment hn-1 = atom hn-1.
__global__ void seg_kernel(const float* __restrict__ score,
                           const int* __restrict__ hlens,
                           int* __restrict__ vi_ws,
                           int* __restrict__ hn_ws,
                           float* __restrict__ hn_out,
                           int T, int M) {
  int b = blockIdx.x;
  int tid = threadIdx.x;
  __shared__ float s[MAX_T];
  __shared__ unsigned char fl[MAX_T];
  __shared__ int vi[MAX_T];
  __shared__ int wsum[4];

  const float* sr = score + (size_t)b * T;
  int hl = hlens[b];

  for (int t = tid; t < T; t += 256) s[t] = sr[t];
  __syncthreads();

  for (int t = tid; t < T; t += 256) {
    bool f;
    if (t >= hl) {
      f = false;
    } else if (t == 0 || t == hl - 1) {
      f = true;
    } else {
      float c = s[t];
      f = (c >= s[t - 1]) && (c >= s[t + 1]);
    }
    fl[t] = f ? (unsigned char)1 : (unsigned char)0;
  }
  __syncthreads();

  int C = (T + 255) / 256;
  int lo = tid * C;
  int hi = lo + C; if (hi > T) hi = T; if (lo > T) lo = T;
  int cnt = 0;
  for (int t = lo; t < hi; ++t) cnt += fl[t];

  int lane = tid & 63, wid = tid >> 6;
  int incl = cnt;
#pragma unroll
  for (int off = 1; off < 64; off <<= 1) {
    int v = __shfl_up(incl, off, 64);
    if (lane >= off) incl += v;
  }
  if (lane == 63) wsum[wid] = incl;
  __syncthreads();
  int wofs = 0;
#pragma unroll
  for (int w = 0; w < 4; ++w) wofs += (w < wid) ? wsum[w] : 0;
  int hn = wsum[0] + wsum[1] + wsum[2] + wsum[3];
  int excl = wofs + incl - cnt;
  for (int t = lo; t < hi; ++t) {
    if (fl[t]) vi[excl++] = t;
  }
  __syncthreads();

  for (int j = tid; j < M; j += 256) {
    vi_ws[(size_t)b * M + j] = (j < hn) ? vi[j] : 0;
  }
  if (tid == 0) {
    hn_ws[b] = hn;
    hn_out[b] = (float)hn;
  }
}

// ---------------- Kernel 3: grouped rolling-atom pool (XCD-swizzled) ----
// One 128-thread block per SEG_P consecutive segments of one batch.
// Logical gid is XCD-chunked: hardware blocks round-robin across 8 XCDs, so
// mapping hw-bid -> contiguous logical chunk per XCD makes the atom-overlap
// re-read between consecutive logical groups an L2 hit (bijective, m204 form).
__global__ __launch_bounds__(128) void pool_kernel(
    const float* __restrict__ feat, const float* __restrict__ score,
    const int* __restrict__ vi_ws, const int* __restrict__ hn_ws,
    float* __restrict__ out, int T, int D, int M, int ngrp, int nblk) {
  int bid = blockIdx.x;
  int q = nblk / NXCD, r = nblk - q * NXCD;
  int xcd = bid % NXCD, idx = bid / NXCD;
  int gid = (xcd < r ? xcd * (q + 1) : r * (q + 1) + (xcd - r) * q) + idx;

  int lane = threadIdx.x;                 // 128 lanes, float4 covers D=512
  int b = gid / ngrp;
  int g = gid - b * ngrp;
  int k0 = g * SEG_P;
  if (k0 >= M) return;

  int hn = hn_ws[b];
  const int* vi = vi_ws + (size_t)b * M;
  const float* sr = score + (size_t)b * T;
  const float4* fr = (const float4*)(feat + (size_t)b * T * (size_t)D);
  int n4 = D >> 2;                        // 128

  int kend = k0 + SEG_P; if (kend > M) kend = M;

  float4 ap = make_float4(0.f, 0.f, 0.f, 0.f);
  float ssp = 0.f;
  if (k0 < hn) {
    int as = (k0 == 0) ? 0 : vi[k0 - 1];
    int ae = vi[k0];
    for (int t = as; t < ae; ++t) {
      float sc = sr[t];
      float4 f = fr[(size_t)t * n4 + lane];
      ap.x += sc * f.x; ap.y += sc * f.y; ap.z += sc * f.z; ap.w += sc * f.w;
      ssp += sc;
    }
  }

  for (int k = k0; k < kend; ++k) {
    float4* o4 = (float4*)(out + ((size_t)b * M + k) * D);
    if (k >= hn) {
      o4[lane] = make_float4(0.f, 0.f, 0.f, 0.f);
      continue;
    }
    if (k == hn - 1) {
      float inv = 1.f / (ssp + 1e-10f);
      o4[lane] = make_float4(ap.x * inv, ap.y * inv, ap.z * inv, ap.w * inv);
      ssp = 0.f; ap = make_float4(0.f, 0.f, 0.f, 0.f);
      continue;
    }
    float4 ac = make_float4(0.f, 0.f, 0.f, 0.f);
    float ssc = 0.f;
    int as = vi[k];
    int ae = vi[k + 1];
    for (int t = as; t < ae; ++t) {
      float sc = sr[t];
      float4 f = fr[(size_t)t * n4 + lane];
      ac.x += sc * f.x; ac.y += sc * f.y; ac.z += sc * f.z; ac.w += sc * f.w;
      ssc += sc;
    }
    float inv = 1.f / (ssp + ssc + 1e-10f);
    o4[lane] = make_float4((ap.x + ac.x) * inv, (ap.y + ac.y) * inv,
                           (ap.z + ac.z) * inv, (ap.w + ac.w) * inv);
    ap = ac; ssp = ssc;
  }
}

extern "C" void kernel_launch(void* const* d_in, const int* in_sizes, int n_in,
                              void* d_out, int out_size, void* d_ws, size_t ws_size,
                              hipStream_t stream) {
  const float* feat = (const float*)d_in[0];
  const float* W    = (const float*)d_in[1];
  const float* bias = (const float*)d_in[2];
  const int* hlens  = (const int*)d_in[3];

  int D = in_sizes[1];                 // 512
  int B = in_sizes[3];                 // 16
  int T = in_sizes[0] / (B * D);       // 2000
  int M = (out_size - B - B * T) / (B * D);  // data-dependent max segments

  float* out      = (float*)d_out;
  float* hn_out   = out + (size_t)B * M * D;      // [B] (as float)
  float* score    = hn_out + B;                   // [B, T]

  // ws layout: vi[B*M] int | hn_ws[B] int
  int* vi_ws = (int*)d_ws;
  int* hn_ws = vi_ws + (size_t)B * M;

  int nrows = B * T;
  score_kernel<<<(nrows + 3) / 4, 256, 0, stream>>>(feat, W, bias, score, nrows, D);
  seg_kernel<<<B, 256, 0, stream>>>(score, hlens, vi_ws, hn_ws, hn_out, T, M);

  int ngrp = (M + SEG_P - 1) / SEG_P;
  int nblk = B * ngrp;
  pool_kernel<<<nblk, 128, 0, stream>>>(feat, score, vi_ws, hn_ws,
                                        out, T, D, M, ngrp, nblk);
}

// Round 8
// 35.360 us; speedup vs baseline: 1.1480x; 1.0608x over previous
//
#include <hip/hip_runtime.h>
#include <math.h>

#define MAX_T 2048
#define SEG_P 4   // segments per 128-lane pool block (measured optimum: {1:40.6, 2:37.5, 4:35.3, 8:~39} µs)

// ---------------- Kernel 1: score = sigmoid(feat . W + b) ----------------
// One wave (64 lanes) per (b,t) row. float4 coalesced loads.
__global__ void score_kernel(const float* __restrict__ feat,
                             const float* __restrict__ W,
                             const float* __restrict__ bias,
                             float* __restrict__ score,
                             int nrows, int D) {
  int row = blockIdx.x * 4 + (threadIdx.x >> 6);
  int lane = threadIdx.x & 63;
  if (row >= nrows) return;
  const float4* f4 = (const float4*)(feat + (size_t)row * D);
  const float4* w4 = (const float4*)W;
  float acc = 0.f;
  int n4 = D >> 2;
  for (int idx = lane; idx < n4; idx += 64) {
    float4 a = f4[idx];
    float4 w = w4[idx];
    acc += a.x * w.x + a.y * w.y + a.z * w.z + a.w * w.w;
  }
#pragma unroll
  for (int off = 32; off > 0; off >>= 1) acc += __shfl_xor(acc, off, 64);
  if (lane == 0) {
    float x = acc + bias[0];
    score[row] = 1.f / (1.f + expf(-x));
  }
}

// ---------------- Kernel 2: valley detect -> vi table ----------------
// One block (256 threads) per batch element. vi[j] = frame index of valley j.
// Atom j := [vi[j-1], vi[j]) with vi[-1]:=0 (atom 0 empty since vi[0]==0).
// Segment k = atom k U atom k+1 (k<hn-1); segment hn-1 = atom hn-1.
__global__ void seg_kernel(const float* __restrict__ score,
                           const int* __restrict__ hlens,
                           int* __restrict__ vi_ws,
                           int* __restrict__ hn_ws,
                           float* __restrict__ hn_out,
                           int T, int M) {
  int b = blockIdx.x;
  int tid = threadIdx.x;
  __shared__ float s[MAX_T];
  __shared__ unsigned char fl[MAX_T];
  __shared__ int vi[MAX_T];
  __shared__ int wsum[4];

  const float* sr = score + (size_t)b * T;
  int hl = hlens[b];

  for (int t = tid; t < T; t += 256) s[t] = sr[t];
  __syncthreads();

  for (int t = tid; t < T; t += 256) {
    bool f;
    if (t >= hl) {
      f = false;
    } else if (t == 0 || t == hl - 1) {
      f = true;
    } else {
      float c = s[t];
      f = (c >= s[t - 1]) && (c >= s[t + 1]);
    }
    fl[t] = f ? (unsigned char)1 : (unsigned char)0;
  }
  __syncthreads();

  int C = (T + 255) / 256;
  int lo = tid * C;
  int hi = lo + C; if (hi > T) hi = T; if (lo > T) lo = T;
  int cnt = 0;
  for (int t = lo; t < hi; ++t) cnt += fl[t];

  int lane = tid & 63, wid = tid >> 6;
  int incl = cnt;
#pragma unroll
  for (int off = 1; off < 64; off <<= 1) {
    int v = __shfl_up(incl, off, 64);
    if (lane >= off) incl += v;
  }
  if (lane == 63) wsum[wid] = incl;
  __syncthreads();
  int wofs = 0;
#pragma unroll
  for (int w = 0; w < 4; ++w) wofs += (w < wid) ? wsum[w] : 0;
  int hn = wsum[0] + wsum[1] + wsum[2] + wsum[3];
  int excl = wofs + incl - cnt;
  for (int t = lo; t < hi; ++t) {
    if (fl[t]) vi[excl++] = t;
  }
  __syncthreads();

  for (int j = tid; j < M; j += 256) {
    vi_ws[(size_t)b * M + j] = (j < hn) ? vi[j] : 0;
  }
  if (tid == 0) {
    hn_ws[b] = hn;
    hn_out[b] = (float)hn;
  }
}

// ---- atom accumulation with 2x unrolled, 2-accumulator ILP ----
__device__ __forceinline__ void atom_accum(const float* __restrict__ sr,
                                           const float4* __restrict__ fr,
                                           int as, int ae, int lane,
                                           float4& a, float& ss) {
  float4 a0 = make_float4(0.f, 0.f, 0.f, 0.f);
  float4 a1 = make_float4(0.f, 0.f, 0.f, 0.f);
  float ss0 = 0.f, ss1 = 0.f;
  int t = as;
  for (; t + 1 < ae; t += 2) {
    float sc0 = sr[t];
    float sc1 = sr[t + 1];
    float4 f0 = fr[(size_t)t * 128 + lane];
    float4 f1 = fr[(size_t)(t + 1) * 128 + lane];
    a0.x += sc0 * f0.x; a0.y += sc0 * f0.y; a0.z += sc0 * f0.z; a0.w += sc0 * f0.w;
    a1.x += sc1 * f1.x; a1.y += sc1 * f1.y; a1.z += sc1 * f1.z; a1.w += sc1 * f1.w;
    ss0 += sc0; ss1 += sc1;
  }
  if (t < ae) {
    float sc0 = sr[t];
    float4 f0 = fr[(size_t)t * 128 + lane];
    a0.x += sc0 * f0.x; a0.y += sc0 * f0.y; a0.z += sc0 * f0.z; a0.w += sc0 * f0.w;
    ss0 += sc0;
  }
  a.x += a0.x + a1.x; a.y += a0.y + a1.y; a.z += a0.z + a1.z; a.w += a0.w + a1.w;
  ss += ss0 + ss1;
}

// ---------------- Kernel 3: grouped rolling-atom pool ----------------
// One 128-thread block per SEG_P consecutive segments of one batch.
// Rolling 2-atom register window; feat read 1.25x, served mostly from L3.
__global__ __launch_bounds__(128) void pool_kernel(
    const float* __restrict__ feat, const float* __restrict__ score,
    const int* __restrict__ vi_ws, const int* __restrict__ hn_ws,
    float* __restrict__ out, int T, int D, int M, int ngrp) {
  int gid = blockIdx.x;
  int lane = threadIdx.x;                 // 128 lanes, float4 covers D=512
  int b = gid / ngrp;
  int g = gid - b * ngrp;
  int k0 = g * SEG_P;
  if (k0 >= M) return;

  int hn = hn_ws[b];
  const int* vi = vi_ws + (size_t)b * M;
  const float* sr = score + (size_t)b * T;
  const float4* fr = (const float4*)(feat + (size_t)b * T * (size_t)D);

  int kend = k0 + SEG_P; if (kend > M) kend = M;

  float4 ap = make_float4(0.f, 0.f, 0.f, 0.f);
  float ssp = 0.f;
  if (k0 < hn) {
    int as = (k0 == 0) ? 0 : vi[k0 - 1];
    int ae = vi[k0];
    atom_accum(sr, fr, as, ae, lane, ap, ssp);
  }

  for (int k = k0; k < kend; ++k) {
    float4* o4 = (float4*)(out + ((size_t)b * M + k) * D);
    if (k >= hn) {
      o4[lane] = make_float4(0.f, 0.f, 0.f, 0.f);
      continue;
    }
    if (k == hn - 1) {
      float inv = 1.f / (ssp + 1e-10f);
      o4[lane] = make_float4(ap.x * inv, ap.y * inv, ap.z * inv, ap.w * inv);
      ssp = 0.f; ap = make_float4(0.f, 0.f, 0.f, 0.f);
      continue;
    }
    float4 ac = make_float4(0.f, 0.f, 0.f, 0.f);
    float ssc = 0.f;
    atom_accum(sr, fr, vi[k], vi[k + 1], lane, ac, ssc);
    float inv = 1.f / (ssp + ssc + 1e-10f);
    o4[lane] = make_float4((ap.x + ac.x) * inv, (ap.y + ac.y) * inv,
                           (ap.z + ac.z) * inv, (ap.w + ac.w) * inv);
    ap = ac; ssp = ssc;
  }
}

extern "C" void kernel_launch(void* const* d_in, const int* in_sizes, int n_in,
                              void* d_out, int out_size, void* d_ws, size_t ws_size,
                              hipStream_t stream) {
  const float* feat = (const float*)d_in[0];
  const float* W    = (const float*)d_in[1];
  const float* bias = (const float*)d_in[2];
  const int* hlens  = (const int*)d_in[3];

  int D = in_sizes[1];                 // 512
  int B = in_sizes[3];                 // 16
  int T = in_sizes[0] / (B * D);       // 2000
  int M = (out_size - B - B * T) / (B * D);  // data-dependent max segments

  float* out      = (float*)d_out;
  float* hn_out   = out + (size_t)B * M * D;      // [B] (as float)
  float* score    = hn_out + B;                   // [B, T]

  // ws layout: vi[B*M] int | hn_ws[B] int
  int* vi_ws = (int*)d_ws;
  int* hn_ws = vi_ws + (size_t)B * M;

  int nrows = B * T;
  score_kernel<<<(nrows + 3) / 4, 256, 0, stream>>>(feat, W, bias, score, nrows, D);
  seg_kernel<<<B, 256, 0, stream>>>(score, hlens, vi_ws, hn_ws, hn_out, T, M);

  int ngrp = (M + SEG_P - 1) / SEG_P;
  pool_kernel<<<B * ngrp, 128, 0, stream>>>(feat, score, vi_ws, hn_ws,
                                            out, T, D, M, ngrp);
}